// Round 6
// baseline (426.928 us; speedup 1.0000x reference)
//
#include <hip/hip_runtime.h>
#include <math.h>

#define D_DIM 4096
#define E_DIM 64
#define TM 16                     // tokens per block
#define KQ 1024                   // k per wave (quarter of D)
#define CHK 32                    // k per chunk (one MFMA K-step)
#define NCH (KQ / CHK)            // 32
#define SROW 68                   // scores LDS stride (f32)
#define WSCALE 1024.0f            // keep f16 residuals of W out of subnormal range
#define ISCALE (1.0f / 1024.0f)

typedef __attribute__((ext_vector_type(8))) __fp16 f16x8;
typedef __attribute__((ext_vector_type(2))) __fp16 f16x2;
typedef __attribute__((ext_vector_type(4))) float f32x4;

// 2-level f16 split: f = hi + lo + O(2^-20 rel). v_cvt_pkrtz packs 2 f32->2 f16 (RTZ).
__device__ inline void split2(const f32x4 a0, const f32x4 a1, f16x8& fh, f16x8& fl) {
    float f[8] = {a0[0], a0[1], a0[2], a0[3], a1[0], a1[1], a1[2], a1[3]};
    union { f16x8 v; f16x2 p[4]; } H, L;
    #pragma unroll
    for (int j = 0; j < 4; ++j) {
        const f16x2 h = __builtin_amdgcn_cvt_pkrtz(f[2*j], f[2*j+1]);
        const float r0 = f[2*j]     - (float)h[0];
        const float r1 = f[2*j + 1] - (float)h[1];
        H.p[j] = h;
        L.p[j] = __builtin_amdgcn_cvt_pkrtz(r0, r1);
    }
    fh = H.v; fl = L.v;
}

// ---- fused router: barrier-free streaming GEMM, explicit dbuf register pipeline ----
// Wave wv owns k-quarter [wv*1024, wv*1024+1024) of the block's 16 tokens.
// Whole next chunk (A: 2 loads HBM, W: 8 loads L2) lives in named register arrays,
// issued a full chunk ahead of use -> real MLP (r4's VGPR=52 showed the compiler
// won't do this on its own).
__global__ __launch_bounds__(256, 4) void router_fused(
    const float* __restrict__ hs,
    const float* __restrict__ W,
    const float* __restrict__ bias,
    float* __restrict__ out,
    int nTok)
{
    __shared__ float sc_lds[4][TM][SROW];   // 4 partial [16 tok x 64 exp] tiles, 17.4 KB

    const int tid  = threadIdx.x;
    const int lane = tid & 63;
    const int wv   = tid >> 6;        // k-quarter
    const int l15  = lane & 15;
    const int lq   = lane >> 4;
    const int tb   = blockIdx.x * TM;

    // A: lane holds A[m = l15][k = wv*KQ + ch*32 + lq*8 + j]
    const float* aptr = hs + (size_t)(tb + l15) * D_DIM + wv * KQ + lq * 8;
    // W rows: e = t*16 + l15, same k window; four precomputed row pointers
    const float* wbase = W + (size_t)l15 * D_DIM + wv * KQ + lq * 8;
    const float* wp0 = wbase;
    const float* wp1 = wbase + (size_t)16 * D_DIM;
    const float* wp2 = wbase + (size_t)32 * D_DIM;
    const float* wp3 = wbase + (size_t)48 * D_DIM;

    f32x4 acc[4];
    #pragma unroll
    for (int t = 0; t < 4; ++t) acc[t] = (f32x4){0.f, 0.f, 0.f, 0.f};

    f32x4 A0[2], A1[2], W0[8], W1[8];

    auto loadChunk = [&](int ch, f32x4* a, f32x4* w) {
        const float* p = aptr + ch * CHK;
        a[0] = *(const f32x4*)(p);
        a[1] = *(const f32x4*)(p + 4);
        const float* q0 = wp0 + ch * CHK;
        w[0] = *(const f32x4*)(q0);  w[1] = *(const f32x4*)(q0 + 4);
        const float* q1 = wp1 + ch * CHK;
        w[2] = *(const f32x4*)(q1);  w[3] = *(const f32x4*)(q1 + 4);
        const float* q2 = wp2 + ch * CHK;
        w[4] = *(const f32x4*)(q2);  w[5] = *(const f32x4*)(q2 + 4);
        const float* q3 = wp3 + ch * CHK;
        w[6] = *(const f32x4*)(q3);  w[7] = *(const f32x4*)(q3 + 4);
    };
    auto computeChunk = [&](const f32x4* a, const f32x4* w) {
        f16x8 ah, al;
        split2(a[0], a[1], ah, al);
        #pragma unroll
        for (int t = 0; t < 4; ++t) {
            f16x8 bh, bl;
            split2(w[2*t] * WSCALE, w[2*t + 1] * WSCALE, bh, bl);
            acc[t] = __builtin_amdgcn_mfma_f32_16x16x32_f16(ah, bh, acc[t], 0, 0, 0);
            acc[t] = __builtin_amdgcn_mfma_f32_16x16x32_f16(ah, bl, acc[t], 0, 0, 0);
            acc[t] = __builtin_amdgcn_mfma_f32_16x16x32_f16(al, bh, acc[t], 0, 0, 0);
        }
    };

    loadChunk(0, A0, W0);
    #pragma unroll 1
    for (int ch = 0; ch < NCH; ch += 2) {            // NCH even: ch+1 always valid
        loadChunk(ch + 1, A1, W1);                   // next chunk in flight
        computeChunk(A0, W0);
        if (ch + 2 < NCH) loadChunk(ch + 2, A0, W0); // chunk after next
        computeChunk(A1, W1);
    }

    // ---- cross-wave k-reduction via LDS, then fused epilogue ----
    // C/D layout: col(expert) = l15 -> e = t*16+l15, row(token) = lq*4+r
    #pragma unroll
    for (int t = 0; t < 4; ++t)
        #pragma unroll
        for (int r = 0; r < 4; ++r)
            sc_lds[wv][lq * 4 + r][t * 16 + l15] = acc[t][r] * ISCALE;
    __syncthreads();

    if (tid < TM * 4) {
        const int token = tid >> 2;
        const int g     = tid & 3;
        const int gtok  = tb + token;

        float* out_idx = out;
        float* out_val = out + (size_t)nTok * 2;
        float* sc      = out + (size_t)nTok * 4;

        float v[16];
        #pragma unroll
        for (int j = 0; j < 4; ++j) {
            f32x4 x = *(const f32x4*)&sc_lds[0][token][g * 16 + j * 4];
            #pragma unroll
            for (int q = 1; q < 4; ++q) {
                const f32x4 y = *(const f32x4*)&sc_lds[q][token][g * 16 + j * 4];
                x[0] += y[0]; x[1] += y[1]; x[2] += y[2]; x[3] += y[3];
            }
            const f32x4 b = *(const f32x4*)(bias + g * 16 + j * 4);
            v[j*4 + 0] = x[0] + b[0];
            v[j*4 + 1] = x[1] + b[1];
            v[j*4 + 2] = x[2] + b[2];
            v[j*4 + 3] = x[3] + b[3];
        }

        // local top-2 (ascending index, strict > keeps lowest index)
        float b1 = -INFINITY, b2 = -INFINITY;
        int i1 = 0, i2 = 0;
        #pragma unroll
        for (int j = 0; j < 16; ++j) {
            const float x = v[j];
            const int idx = g * 16 + j;
            if (x > b1)      { b2 = b1; i2 = i1; b1 = x; i1 = idx; }
            else if (x > b2) { b2 = x; i2 = idx; }
        }
        // butterfly merge across the 4 lanes of this token (consecutive lanes, same wave)
        #pragma unroll
        for (int d = 1; d <= 2; d <<= 1) {
            const float ob1 = __shfl_xor(b1, d);
            const int   oi1 = __shfl_xor(i1, d);
            const float ob2 = __shfl_xor(b2, d);
            const int   oi2 = __shfl_xor(i2, d);
            if (ob1 > b1 || (ob1 == b1 && oi1 < i1)) {
                if (b1 > ob2 || (b1 == ob2 && i1 < oi2)) { b2 = b1; i2 = i1; }
                else                                     { b2 = ob2; i2 = oi2; }
                b1 = ob1; i1 = oi1;
            } else {
                if (ob1 > b2 || (ob1 == b2 && oi1 < i2)) { b2 = ob1; i2 = oi1; }
            }
        }
        const float m = b1;   // top-1 value is the row max

        float e[16];
        float s = 0.f;
        #pragma unroll
        for (int j = 0; j < 16; ++j) { e[j] = __expf(v[j] - m); s += e[j]; }
        s += __shfl_xor(s, 1);
        s += __shfl_xor(s, 2);
        const float inv = 1.f / s;

        if (g == 0) {
            out_idx[(size_t)gtok * 2 + 0] = (float)i1;
            out_idx[(size_t)gtok * 2 + 1] = (float)i2;
            out_val[(size_t)gtok * 2 + 0] = inv;                    // exp(b1-m)=1
            out_val[(size_t)gtok * 2 + 1] = __expf(b2 - m) * inv;
        }

        float* dstg = sc + (size_t)gtok * E_DIM + g * 16;
        #pragma unroll
        for (int j = 0; j < 4; ++j) {
            f32x4 o;
            o[0] = e[j*4 + 0] * inv;
            o[1] = e[j*4 + 1] * inv;
            o[2] = e[j*4 + 2] * inv;
            o[3] = e[j*4 + 3] * inv;
            *(f32x4*)(dstg + j * 4) = o;
        }
    }
}

extern "C" void kernel_launch(void* const* d_in, const int* in_sizes, int n_in,
                              void* d_out, int out_size, void* d_ws, size_t ws_size,
                              hipStream_t stream) {
    const float* hs = (const float*)d_in[0];
    const float* W  = (const float*)d_in[1];
    const float* b  = (const float*)d_in[2];
    float* out = (float*)d_out;
    const int nTok = in_sizes[0] / D_DIM;   // 16384

    router_fused<<<dim3(nTok / TM), dim3(256), 0, stream>>>(hs, W, b, out, nTok);
}

// Round 7
// 384.205 us; speedup vs baseline: 1.1112x; 1.1112x over previous
//
#include <hip/hip_runtime.h>
#include <math.h>

#define D_DIM 4096
#define E_DIM 64
#define TM 64                    // tokens per block
#define KSPLIT 4
#define KPART (D_DIM / KSPLIT)   // 1024
#define CHK 64                   // k per chunk
#define NCH (KPART / CHK)        // 16
#define WROW 72                  // padded k-stride (elements) for W LDS rows (zero bank conflict, verified r1)
#define WSCALE 1024.0f           // keep f16 split residuals of W out of subnormal range
#define ISCALE (1.0f / 1024.0f)

typedef __attribute__((ext_vector_type(8))) __fp16 f16x8;
typedef __attribute__((ext_vector_type(2))) __fp16 f16x2;
typedef __attribute__((ext_vector_type(4))) float f32x4;

// 2-level f16 split: f = hi + lo + O(2^-20 rel). v_cvt_pkrtz packs 2 f32->2 f16 (RTZ).
__device__ inline void split2(const f32x4 a0, const f32x4 a1, f16x8& fh, f16x8& fl) {
    float f[8] = {a0[0], a0[1], a0[2], a0[3], a1[0], a1[1], a1[2], a1[3]};
    union { f16x8 v; f16x2 p[4]; } H, L;
    #pragma unroll
    for (int j = 0; j < 4; ++j) {
        const f16x2 h = __builtin_amdgcn_cvt_pkrtz(f[2*j], f[2*j+1]);
        const float r0 = f[2*j]     - (float)h[0];
        const float r1 = f[2*j + 1] - (float)h[1];
        H.p[j] = h;
        L.p[j] = __builtin_amdgcn_cvt_pkrtz(r0, r1);
    }
    fh = H.v; fl = L.v;
}

// barrier that publishes LDS writes but leaves register-destined global loads in flight
__device__ inline void lds_barrier() {
    asm volatile("s_waitcnt lgkmcnt(0)" ::: "memory");
    __builtin_amdgcn_s_barrier();
    __builtin_amdgcn_sched_barrier(0);   // rule #18: pin ds_read/MFMA below the barrier
}

// ---------------- kernel 1: K-split MFMA GEMM, atomic partial-logit accumulate ----------------
// vmcnt-queue discipline (m135: waits are issue-ordered): W loads are issued FIRST each
// phase, A-prefetch after -> storeW's implicit wait is vmcnt(4); the A loads stay in
// flight across storeW AND the lgkm-only barrier => ~1.5 phases of A latency cover.
__global__ __launch_bounds__(256, 4) void router_gemm(
    const float* __restrict__ hs,
    const float* __restrict__ W,
    float* __restrict__ logits,   // [nTok, 64], pre-zeroed
    int nTok)
{
    // double-buffered W staging: 2 levels x 2 buffers x 64x72 f16 = 36.9 KB (4 blocks/CU ok)
    __shared__ __fp16 wsh[2][E_DIM * WROW];
    __shared__ __fp16 wsl[2][E_DIM * WROW];

    const int tid  = threadIdx.x;
    const int lane = tid & 63;
    const int wv   = tid >> 6;                  // wave 0..3 -> token group
    const int part = blockIdx.x & (KSPLIT - 1);
    const int tb   = (blockIdx.x >> 2) * TM;
    const int kb   = part * KPART;

    const int l15 = lane & 15;                  // A: token within wave-tile; B: expert within tile
    const int lq  = lane >> 4;                  // k-quad (8 k's)

    // A fragments straight from global: lane holds A[m=l15][k=lq*8+j] (contiguous 32 B)
    const float* aptr = hs + (size_t)(tb + wv * 16 + l15) * D_DIM + kb + lq * 8;
    // W staging: thread covers expert we, 16 consecutive k (2 groups of 8)
    const int we = tid >> 2;
    const int wq = tid & 3;
    const float* wptr = W + (size_t)we * D_DIM + kb + wq * 16;

    f32x4 acc[4];
    #pragma unroll
    for (int t = 0; t < 4; ++t) acc[t] = (f32x4){0.f, 0.f, 0.f, 0.f};

    f32x4 A0[4], A1[4], wr[4];

    auto loadA = [&](int ch, f32x4* dst) {
        const float* p = aptr + ch * CHK;
        dst[0] = *(const f32x4*)(p);
        dst[1] = *(const f32x4*)(p + 4);
        dst[2] = *(const f32x4*)(p + 32);
        dst[3] = *(const f32x4*)(p + 36);
    };
    auto loadW = [&](int ch) {
        const float* p = wptr + ch * CHK;
        wr[0] = *(const f32x4*)(p);
        wr[1] = *(const f32x4*)(p + 4);
        wr[2] = *(const f32x4*)(p + 8);
        wr[3] = *(const f32x4*)(p + 12);
    };
    auto storeW = [&](int buf) {
        f16x8 h0, l0, h1, l1;
        split2(wr[0] * WSCALE, wr[1] * WSCALE, h0, l0);
        split2(wr[2] * WSCALE, wr[3] * WSCALE, h1, l1);
        const int base = we * WROW + wq * 16;
        *(f16x8*)&wsh[buf][base] = h0;  *(f16x8*)&wsh[buf][base + 8] = h1;  // ds_write_b128
        *(f16x8*)&wsl[buf][base] = l0;  *(f16x8*)&wsl[buf][base + 8] = l1;
    };
    auto compute = [&](const f32x4* a, int buf) {
        #pragma unroll
        for (int s = 0; s < 2; ++s) {
            f16x8 ah, al;
            split2(a[2 * s], a[2 * s + 1], ah, al);
            const int koff = s * 32 + lq * 8;
            #pragma unroll
            for (int t = 0; t < 4; ++t) {
                const int rb = (t * 16 + l15) * WROW + koff;
                const f16x8 bh = *(const f16x8*)&wsh[buf][rb];
                const f16x8 bl = *(const f16x8*)&wsl[buf][rb];
                acc[t] = __builtin_amdgcn_mfma_f32_16x16x32_f16(ah, bh, acc[t], 0, 0, 0);
                acc[t] = __builtin_amdgcn_mfma_f32_16x16x32_f16(ah, bl, acc[t], 0, 0, 0);
                acc[t] = __builtin_amdgcn_mfma_f32_16x16x32_f16(al, bh, acc[t], 0, 0, 0);
            }
        }
    };

    // prologue: W(0) oldest, then A(0), A(1) -> storeW(0) waits vmcnt(8), A stays in flight
    loadW(0);
    __builtin_amdgcn_sched_barrier(0);
    loadA(0, A0);
    loadA(1, A1);
    storeW(0);
    lds_barrier();

    // 2-phase software pipeline; chunk parity == LDS buffer parity == A-buffer parity
    #pragma unroll 1
    for (int ch = 0; ch < NCH; ch += 2) {
        // even phase: compute chunk ch from buf 0 / A0; stage W(ch+1) -> buf 1
        loadW(ch + 1);                            // ch+1 <= 15 always
        __builtin_amdgcn_sched_barrier(0);        // pin: W oldest in this phase's queue
        compute(A0, 0);
        if (ch + 2 < NCH) loadA(ch + 2, A0);      // reload after use; younger than W
        storeW(1);                                // waits vmcnt(4): A prefetch survives
        lds_barrier();                            // publish buf1; A still in flight

        // odd phase: compute chunk ch+1 from buf 1 / A1; stage W(ch+2) -> buf 0
        if (ch + 2 < NCH) {
            loadW(ch + 2);
            __builtin_amdgcn_sched_barrier(0);
        }
        compute(A1, 1);
        if (ch + 3 < NCH) loadA(ch + 3, A1);
        if (ch + 2 < NCH) {
            storeW(0);
            lds_barrier();
        }
    }

    // C/D layout: col(expert) = l15, row(token) = lq*4 + r; unscale the 2^10 W factor
    float* dst = logits + (size_t)(tb + wv * 16) * E_DIM;
    #pragma unroll
    for (int t = 0; t < 4; ++t)
        #pragma unroll
        for (int r = 0; r < 4; ++r)
            unsafeAtomicAdd(&dst[(size_t)(lq * 4 + r) * E_DIM + t * 16 + l15], acc[t][r] * ISCALE);
}

// ---------------- kernel 2: bias + softmax + top-2, LDS-free, 4 lanes/token ----------------
__global__ __launch_bounds__(256, 4) void router_epilogue(
    const float* __restrict__ bias,
    float* __restrict__ out,
    int nTok)
{
    const int tid = threadIdx.x;
    const int tok = blockIdx.x * 64 + (tid >> 2);
    const int g   = tid & 3;

    float* out_idx = out;
    float* out_val = out + (size_t)nTok * 2;
    float* sc      = out + (size_t)nTok * 4;

    float* src = sc + (size_t)tok * E_DIM + g * 16;
    float v[16];
    #pragma unroll
    for (int j = 0; j < 4; ++j) {
        const f32x4 x = *(const f32x4*)(src + j * 4);
        const f32x4 b = *(const f32x4*)(bias + g * 16 + j * 4);
        v[j * 4 + 0] = x[0] + b[0];
        v[j * 4 + 1] = x[1] + b[1];
        v[j * 4 + 2] = x[2] + b[2];
        v[j * 4 + 3] = x[3] + b[3];
    }

    // local top-2 (ascending index, strict > keeps lowest index)
    float b1 = -INFINITY, b2 = -INFINITY;
    int i1 = 0, i2 = 0;
    #pragma unroll
    for (int j = 0; j < 16; ++j) {
        const float x = v[j];
        const int idx = g * 16 + j;
        if (x > b1)      { b2 = b1; i2 = i1; b1 = x; i1 = idx; }
        else if (x > b2) { b2 = x; i2 = idx; }
    }
    // butterfly merge across the 4 lanes of this token
    #pragma unroll
    for (int d = 1; d <= 2; d <<= 1) {
        const float ob1 = __shfl_xor(b1, d);
        const int   oi1 = __shfl_xor(i1, d);
        const float ob2 = __shfl_xor(b2, d);
        const int   oi2 = __shfl_xor(i2, d);
        if (ob1 > b1 || (ob1 == b1 && oi1 < i1)) {
            if (b1 > ob2 || (b1 == ob2 && i1 < oi2)) { b2 = b1; i2 = i1; }
            else                                     { b2 = ob2; i2 = oi2; }
            b1 = ob1; i1 = oi1;
        } else {
            if (ob1 > b2 || (ob1 == b2 && oi1 < i2)) { b2 = ob1; i2 = oi1; }
        }
    }
    const float m = b1;   // top-1 value is the row max

    float e[16];
    float s = 0.f;
    #pragma unroll
    for (int j = 0; j < 16; ++j) { e[j] = __expf(v[j] - m); s += e[j]; }
    s += __shfl_xor(s, 1);
    s += __shfl_xor(s, 2);
    const float inv = 1.f / s;

    if (g == 0) {
        out_idx[(size_t)tok * 2 + 0] = (float)i1;
        out_idx[(size_t)tok * 2 + 1] = (float)i2;
        out_val[(size_t)tok * 2 + 0] = inv;                    // exp(b1-m)=1
        out_val[(size_t)tok * 2 + 1] = __expf(b2 - m) * inv;
    }

    #pragma unroll
    for (int j = 0; j < 4; ++j) {
        f32x4 o;
        o[0] = e[j * 4 + 0] * inv;
        o[1] = e[j * 4 + 1] * inv;
        o[2] = e[j * 4 + 2] * inv;
        o[3] = e[j * 4 + 3] * inv;
        *(f32x4*)(src + j * 4) = o;
    }
}

extern "C" void kernel_launch(void* const* d_in, const int* in_sizes, int n_in,
                              void* d_out, int out_size, void* d_ws, size_t ws_size,
                              hipStream_t stream) {
    const float* hs = (const float*)d_in[0];
    const float* W  = (const float*)d_in[1];
    const float* b  = (const float*)d_in[2];
    float* out = (float*)d_out;
    const int nTok = in_sizes[0] / D_DIM;   // 16384

    float* logits = out + (size_t)nTok * 4;  // scores region doubles as logit accumulator
    hipMemsetAsync(logits, 0, (size_t)nTok * E_DIM * sizeof(float), stream);

    dim3 g1(nTok / TM * KSPLIT), b1(256);
    router_gemm<<<g1, b1, 0, stream>>>(hs, W, logits, nTok);

    dim3 g2(nTok / 64), b2(256);
    router_epilogue<<<g2, b2, 0, stream>>>(b, out, nTok);
}